// Round 6
// baseline (180.289 us; speedup 1.0000x reference)
//
#include <hip/hip_runtime.h>
#include <math.h>

// Attn_83854941487646: out = softmax(tanh(Q) @ H^T) @ H
// B=8, Q=2048, K=2048, Hdim=128, fp32 in/out.
// R6: drop Ps LDS (PV via mfma_16x16x16f16, B-frag == S^T C-layout, from regs)
//     -> LDS 34.3KB -> 4 blocks/CU; splits=8 (grid 1024 = 4/CU exact);
//     f16 O-partials (halves combine traffic, ws fits 8 splits);
//     XCD swizzle in BOTH kernels; Q frags pre-scaled by log2(e).

typedef _Float16 half8 __attribute__((ext_vector_type(8)));
typedef _Float16 half4 __attribute__((ext_vector_type(4)));
typedef float    f32x4 __attribute__((ext_vector_type(4)));

#define QQ 2048
#define KK 2048
#define HH 128
#define BM 128               // q-rows per block (4 waves x 32: dual strip)
#define BN 64
#define NTILES 32
#define NGROUPS 128          // 8 batches x 16 q-blocks
#define KS_STR 132           // halves: 128 + 4 pad
#define VT_STR 68            // halves: 64 + 4 pad
#define L2E 1.44269504f
#define SPLITS_MAX 8
#define OSPLIT  ((size_t)NGROUPS * BM * HH)   // f16 elements per split (O partials)
#define MLSPLIT ((size_t)NGROUPS * BM)        // f32 elements per split (each of m,l)

union U32H { unsigned int u; _Float16 h[2]; };

__launch_bounds__(256, 4)
__global__ void attn_main(const float* __restrict__ out_state,
                          const float* __restrict__ history,
                          float* __restrict__ out,
                          void* __restrict__ wsv,
                          int splits) {
    __shared__ _Float16 Ks[BN * KS_STR];         // 16896 B  [key][h]
    __shared__ _Float16 Vt[HH * VT_STR];         // 17408 B  [h][key]

    const int tid  = threadIdx.x;
    const int wave = tid >> 6;          // 0..3
    const int lane = tid & 63;
    const int quad = lane >> 4;
    const int lc   = lane & 15;

    // XCD swizzle: round-robin dispatch -> batch b pinned to XCD b.
    const int bid = blockIdx.x;
    const int b   = bid & 7;
    const int t   = bid >> 3;
    const int qb  = t & 15;
    const int s   = t >> 4;             // split id
    const int g   = b * 16 + qb;        // group id
    const int m0  = qb * BM;

    const int kt0 = (NTILES * s) / splits;
    const int kt1 = (NTILES * (s + 1)) / splits;

    // Q fragments for two strips, pre-scaled by log2(e) (S comes out in log2 units).
    half8 qfa[4], qfb[4];
    {
        const float* qrowA = out_state + ((size_t)b * QQ + m0 + wave * 32 + lc) * HH;
        const float* qrowB = qrowA + 16 * HH;
        #pragma unroll
        for (int s4 = 0; s4 < 4; ++s4) {
            const int h0 = 32 * s4 + quad * 8;
            float4 a = *(const float4*)(qrowA + h0);
            float4 c = *(const float4*)(qrowA + h0 + 4);
            qfa[s4][0] = (_Float16)(L2E * tanhf(a.x)); qfa[s4][1] = (_Float16)(L2E * tanhf(a.y));
            qfa[s4][2] = (_Float16)(L2E * tanhf(a.z)); qfa[s4][3] = (_Float16)(L2E * tanhf(a.w));
            qfa[s4][4] = (_Float16)(L2E * tanhf(c.x)); qfa[s4][5] = (_Float16)(L2E * tanhf(c.y));
            qfa[s4][6] = (_Float16)(L2E * tanhf(c.z)); qfa[s4][7] = (_Float16)(L2E * tanhf(c.w));
            a = *(const float4*)(qrowB + h0);
            c = *(const float4*)(qrowB + h0 + 4);
            qfb[s4][0] = (_Float16)(L2E * tanhf(a.x)); qfb[s4][1] = (_Float16)(L2E * tanhf(a.y));
            qfb[s4][2] = (_Float16)(L2E * tanhf(a.z)); qfb[s4][3] = (_Float16)(L2E * tanhf(a.w));
            qfb[s4][4] = (_Float16)(L2E * tanhf(c.x)); qfb[s4][5] = (_Float16)(L2E * tanhf(c.y));
            qfb[s4][6] = (_Float16)(L2E * tanhf(c.z)); qfb[s4][7] = (_Float16)(L2E * tanhf(c.w));
        }
    }

    const f32x4 zero4 = {0.f, 0.f, 0.f, 0.f};
    f32x4 Oa[8], Ob[8];
    #pragma unroll
    for (int i = 0; i < 8; ++i) { Oa[i] = zero4; Ob[i] = zero4; }
    f32x4 OsumA = zero4, OsumB = zero4;
    float rmaxA = -3.0e38f, rmaxB = -3.0e38f;

    // staging maps (256 threads)
    const int r0  = tid >> 5;           // stage0/1: key row 0..7 (+8j)
    const int c4  = (tid & 31) * 4;     // stage0/1: h col
    const int h0  = 2 * (tid & 63);     // stage2: h-pair
    const int n0t = (tid >> 6) * 16;    // stage2: 16-key group

    const half4 ones4 = {(_Float16)1.f, (_Float16)1.f, (_Float16)1.f, (_Float16)1.f};

    for (int kt = kt0; kt < kt1; ++kt) {
        const int n0 = kt * BN;

        // stage 0: coalesced global prefetch (8 rows x f32x4 per thread)
        float4 gbuf[8];
        const float* hb = history + ((size_t)b * KK + n0) * HH;
        #pragma unroll
        for (int j = 0; j < 8; ++j)
            gbuf[j] = *(const float4*)(hb + (size_t)(r0 + 8 * j) * HH + c4);

        __syncthreads();                 // previous tile's compute done
        #pragma unroll
        for (int j = 0; j < 8; ++j) {
            half4 hv;
            hv[0] = (_Float16)gbuf[j].x; hv[1] = (_Float16)gbuf[j].y;
            hv[2] = (_Float16)gbuf[j].z; hv[3] = (_Float16)gbuf[j].w;
            *(half4*)&Ks[(r0 + 8 * j) * KS_STR + c4] = hv;
        }
        __syncthreads();                 // Ks ready
        // stage 2: transpose Ks -> Vt[h][key]
        {
            half8 ra0, ra1, rb0, rb1;
            #pragma unroll
            for (int i = 0; i < 8; ++i) {
                U32H t2; t2.u = *(const unsigned int*)&Ks[(n0t + i) * KS_STR + h0];
                ra0[i] = t2.h[0]; rb0[i] = t2.h[1];
            }
            #pragma unroll
            for (int i = 8; i < 16; ++i) {
                U32H t2; t2.u = *(const unsigned int*)&Ks[(n0t + i) * KS_STR + h0];
                ra1[i - 8] = t2.h[0]; rb1[i - 8] = t2.h[1];
            }
            *(half8*)&Vt[(h0    ) * VT_STR + n0t    ] = ra0;
            *(half8*)&Vt[(h0    ) * VT_STR + n0t + 8] = ra1;
            *(half8*)&Vt[(h0 + 1) * VT_STR + n0t    ] = rb0;
            *(half8*)&Vt[(h0 + 1) * VT_STR + n0t + 8] = rb1;
        }
        __syncthreads();                 // Vt ready

        // ---- S^T = K.Q^T for both strips (S in log2 units) ----
        f32x4 Sa[4], Sb[4];
        #pragma unroll
        for (int nt = 0; nt < 4; ++nt) {
            f32x4 aa = zero4, ab = zero4;
            #pragma unroll
            for (int s4 = 0; s4 < 4; ++s4) {
                half8 kf = *(half8*)&Ks[(nt * 16 + lc) * KS_STR + 32 * s4 + quad * 8];
                aa = __builtin_amdgcn_mfma_f32_16x16x32_f16(kf, qfa[s4], aa, 0, 0, 0);
                ab = __builtin_amdgcn_mfma_f32_16x16x32_f16(kf, qfb[s4], ab, 0, 0, 0);
            }
            Sa[nt] = aa; Sb[nt] = ab;
        }

        // ---- online softmax (log2 domain) ----
        float tmaxA = Sa[0][0], tmaxB = Sb[0][0];
        #pragma unroll
        for (int nt = 0; nt < 4; ++nt)
            #pragma unroll
            for (int r = 0; r < 4; ++r) {
                tmaxA = fmaxf(tmaxA, Sa[nt][r]);
                tmaxB = fmaxf(tmaxB, Sb[nt][r]);
            }
        tmaxA = fmaxf(tmaxA, __shfl_xor(tmaxA, 16, 64));
        tmaxA = fmaxf(tmaxA, __shfl_xor(tmaxA, 32, 64));
        tmaxB = fmaxf(tmaxB, __shfl_xor(tmaxB, 16, 64));
        tmaxB = fmaxf(tmaxB, __shfl_xor(tmaxB, 32, 64));

        const float nmA = fmaxf(rmaxA, tmaxA);
        const float nmB = fmaxf(rmaxB, tmaxB);
        const float alphaA = exp2f(rmaxA - nmA);
        const float alphaB = exp2f(rmaxB - nmB);
        rmaxA = nmA; rmaxB = nmB;

        #pragma unroll
        for (int ct = 0; ct < 8; ++ct) { Oa[ct] *= alphaA; Ob[ct] *= alphaB; }
        OsumA *= alphaA; OsumB *= alphaB;

        // ---- P = exp2(S - nm) -> f16 regs; PV + ones-rowsum via 16x16x16 ----
        #pragma unroll
        for (int nt = 0; nt < 4; ++nt) {
            half4 pba, pbb;
            #pragma unroll
            for (int r = 0; r < 4; ++r) {
                pba[r] = (_Float16)exp2f(Sa[nt][r] - nmA);
                pbb[r] = (_Float16)exp2f(Sb[nt][r] - nmB);
            }
            OsumA = __builtin_amdgcn_mfma_f32_16x16x16f16(ones4, pba, OsumA, 0, 0, 0);
            OsumB = __builtin_amdgcn_mfma_f32_16x16x16f16(ones4, pbb, OsumB, 0, 0, 0);
            #pragma unroll
            for (int ct = 0; ct < 8; ++ct) {
                half4 va = *(half4*)&Vt[(ct * 16 + lc) * VT_STR + nt * 16 + quad * 4];
                Oa[ct] = __builtin_amdgcn_mfma_f32_16x16x16f16(va, pba, Oa[ct], 0, 0, 0);
                Ob[ct] = __builtin_amdgcn_mfma_f32_16x16x16f16(va, pbb, Ob[ct], 0, 0, 0);
            }
        }
    }

    const int qA = wave * 32 + lc;        // strip A local q-row
    if (splits == 1) {
        const float invA = 1.0f / OsumA[0];
        const float invB = 1.0f / OsumB[0];
        float* orowA = out + ((size_t)b * QQ + m0 + qA) * HH;
        float* orowB = orowA + 16 * HH;
        #pragma unroll
        for (int ct = 0; ct < 8; ++ct) {
            f32x4 va = Oa[ct] * invA;
            f32x4 vb = Ob[ct] * invB;
            *(f32x4*)&orowA[ct * 16 + quad * 4] = va;
            *(f32x4*)&orowB[ct * 16 + quad * 4] = vb;
        }
        return;
    }

    // ---- write partials: O as f16, m/l as f32 (kernel boundary = release) ----
    _Float16* wsO = (_Float16*)wsv;
    float*    wsM = (float*)((char*)wsv + (size_t)splits * OSPLIT * 2);
    float*    wsL = wsM + (size_t)splits * MLSPLIT;

    _Float16* poA = wsO + ((size_t)s * NGROUPS + g) * ((size_t)BM * HH) + (size_t)qA * HH;
    _Float16* poB = poA + 16 * HH;
    #pragma unroll
    for (int ct = 0; ct < 8; ++ct) {
        half4 ha, hb2;
        #pragma unroll
        for (int r = 0; r < 4; ++r) { ha[r] = (_Float16)Oa[ct][r]; hb2[r] = (_Float16)Ob[ct][r]; }
        *(half4*)&poA[ct * 16 + quad * 4] = ha;
        *(half4*)&poB[ct * 16 + quad * 4] = hb2;
    }
    if (quad == 0) {
        const size_t idx = (size_t)(s * NGROUPS + g) * BM + qA;
        wsM[idx]      = rmaxA;
        wsL[idx]      = OsumA[0];
        wsM[idx + 16] = rmaxB;
        wsL[idx + 16] = OsumB[0];
    }
}

__global__ void attn_combine(const void* __restrict__ wsv,
                             float* __restrict__ out,
                             int splits) {
    // XCD swizzle: batch = blockIdx&7 so partial reads hit the L2 that wrote them.
    const int b      = blockIdx.x & 7;
    const int qchunk = blockIdx.x >> 3;          // 0..255, 8 q-rows each
    const int h4 = (threadIdx.x & 31) * 4;
    const int q  = qchunk * 8 + (threadIdx.x >> 5);
    const int g  = b * 16 + (q >> 7);
    const int qr = q & 127;

    const _Float16* wsO = (const _Float16*)wsv;
    const float*    wsM = (const float*)((const char*)wsv + (size_t)splits * OSPLIT * 2);
    const float*    wsL = wsM + (size_t)splits * MLSPLIT;

    float ms[SPLITS_MAX];
    float M = -3.0e38f;
    for (int sp = 0; sp < splits; ++sp) {
        ms[sp] = wsM[(size_t)(sp * NGROUPS + g) * BM + qr];
        M = fmaxf(M, ms[sp]);
    }
    float denom = 0.f;
    f32x4 val = {0.f, 0.f, 0.f, 0.f};
    for (int sp = 0; sp < splits; ++sp) {
        const float w = exp2f(ms[sp] - M);
        denom += w * wsL[(size_t)(sp * NGROUPS + g) * BM + qr];
        const half4 ov = *(const half4*)&wsO[(size_t)(sp * NGROUPS + g) * ((size_t)BM * HH)
                                             + (size_t)qr * HH + h4];
        #pragma unroll
        for (int i = 0; i < 4; ++i) val[i] += w * (float)ov[i];
    }
    const float inv = 1.0f / denom;
    *(f32x4*)&out[((size_t)b * QQ + q) * HH + h4] = val * inv;
}

extern "C" void kernel_launch(void* const* d_in, const int* in_sizes, int n_in,
                              void* d_out, int out_size, void* d_ws, size_t ws_size,
                              hipStream_t stream) {
    const float* out_state = (const float*)d_in[0];
    const float* history   = (const float*)d_in[1];
    float* out = (float*)d_out;

    int splits = 1;
    const int cands[5] = {8, 6, 4, 3, 2};
    for (int i = 0; i < 5; ++i) {
        const size_t bytes = (size_t)cands[i] * (OSPLIT * 2 + 2 * MLSPLIT * 4);
        if (ws_size >= bytes) { splits = cands[i]; break; }
    }

    attn_main<<<dim3(NGROUPS * splits), dim3(256), 0, stream>>>(out_state, history, out, d_ws, splits);
    if (splits > 1)
        attn_combine<<<dim3(2048), dim3(256), 0, stream>>>(d_ws, out, splits);
}

// Round 7
// 179.295 us; speedup vs baseline: 1.0055x; 1.0055x over previous
//
#include <hip/hip_runtime.h>
#include <math.h>

// Attn_83854941487646: out = softmax(tanh(Q) @ H^T) @ H
// B=8, Q=2048, K=2048, Hdim=128, fp32 in/out.
// R7: R6 compute structure (PV from regs via mfma_16x16x16f16, 34.3KB LDS,
//     log2-domain softmax) + R5 memory behavior (f32 partials, full-sector
//     f32x4 stores) + splits=8 (4 blocks/CU exact). No partial-sector stores!

typedef _Float16 half8 __attribute__((ext_vector_type(8)));
typedef _Float16 half4 __attribute__((ext_vector_type(4)));
typedef float    f32x4 __attribute__((ext_vector_type(4)));

#define QQ 2048
#define KK 2048
#define HH 128
#define BM 128               // q-rows per block (4 waves x 32: dual strip)
#define BN 64
#define NTILES 32
#define NGROUPS 128          // 8 batches x 16 q-blocks
#define KS_STR 132           // halves: 128 + 4 pad
#define VT_STR 68            // halves: 64 + 4 pad
#define L2E 1.44269504f
#define SPLITS_MAX 8
#define OSPLIT  ((size_t)NGROUPS * BM * HH)   // f32 elements per split (O partials)
#define MLSPLIT ((size_t)NGROUPS * BM)        // f32 elements per split (each of m,l)

union U32H { unsigned int u; _Float16 h[2]; };

__launch_bounds__(256, 4)
__global__ void attn_main(const float* __restrict__ out_state,
                          const float* __restrict__ history,
                          float* __restrict__ out,
                          float* __restrict__ ws,
                          int splits) {
    __shared__ _Float16 Ks[BN * KS_STR];         // 16896 B  [key][h]
    __shared__ _Float16 Vt[HH * VT_STR];         // 17408 B  [h][key]

    const int tid  = threadIdx.x;
    const int wave = tid >> 6;          // 0..3
    const int lane = tid & 63;
    const int quad = lane >> 4;
    const int lc   = lane & 15;

    // XCD swizzle: round-robin dispatch -> batch b pinned to XCD b,
    // so each XCD's 4MB L2 caches its batch's 1MB history slice.
    const int bid = blockIdx.x;
    const int b   = bid & 7;
    const int t   = bid >> 3;
    const int qb  = t & 15;
    const int s   = t >> 4;             // split id
    const int g   = b * 16 + qb;        // group id
    const int m0  = qb * BM;

    const int kt0 = (NTILES * s) / splits;
    const int kt1 = (NTILES * (s + 1)) / splits;

    // Q fragments for two strips, pre-scaled by log2(e) (S in log2 units).
    half8 qfa[4], qfb[4];
    {
        const float* qrowA = out_state + ((size_t)b * QQ + m0 + wave * 32 + lc) * HH;
        const float* qrowB = qrowA + 16 * HH;
        #pragma unroll
        for (int s4 = 0; s4 < 4; ++s4) {
            const int h0 = 32 * s4 + quad * 8;
            float4 a = *(const float4*)(qrowA + h0);
            float4 c = *(const float4*)(qrowA + h0 + 4);
            qfa[s4][0] = (_Float16)(L2E * tanhf(a.x)); qfa[s4][1] = (_Float16)(L2E * tanhf(a.y));
            qfa[s4][2] = (_Float16)(L2E * tanhf(a.z)); qfa[s4][3] = (_Float16)(L2E * tanhf(a.w));
            qfa[s4][4] = (_Float16)(L2E * tanhf(c.x)); qfa[s4][5] = (_Float16)(L2E * tanhf(c.y));
            qfa[s4][6] = (_Float16)(L2E * tanhf(c.z)); qfa[s4][7] = (_Float16)(L2E * tanhf(c.w));
            a = *(const float4*)(qrowB + h0);
            c = *(const float4*)(qrowB + h0 + 4);
            qfb[s4][0] = (_Float16)(L2E * tanhf(a.x)); qfb[s4][1] = (_Float16)(L2E * tanhf(a.y));
            qfb[s4][2] = (_Float16)(L2E * tanhf(a.z)); qfb[s4][3] = (_Float16)(L2E * tanhf(a.w));
            qfb[s4][4] = (_Float16)(L2E * tanhf(c.x)); qfb[s4][5] = (_Float16)(L2E * tanhf(c.y));
            qfb[s4][6] = (_Float16)(L2E * tanhf(c.z)); qfb[s4][7] = (_Float16)(L2E * tanhf(c.w));
        }
    }

    const f32x4 zero4 = {0.f, 0.f, 0.f, 0.f};
    f32x4 Oa[8], Ob[8];
    #pragma unroll
    for (int i = 0; i < 8; ++i) { Oa[i] = zero4; Ob[i] = zero4; }
    f32x4 OsumA = zero4, OsumB = zero4;
    float rmaxA = -3.0e38f, rmaxB = -3.0e38f;

    // staging maps (256 threads)
    const int r0  = tid >> 5;           // stage0/1: key row 0..7 (+8j)
    const int c4  = (tid & 31) * 4;     // stage0/1: h col
    const int h0  = 2 * (tid & 63);     // stage2: h-pair
    const int n0t = (tid >> 6) * 16;    // stage2: 16-key group

    const half4 ones4 = {(_Float16)1.f, (_Float16)1.f, (_Float16)1.f, (_Float16)1.f};

    for (int kt = kt0; kt < kt1; ++kt) {
        const int n0 = kt * BN;

        // stage 0: coalesced global prefetch (8 rows x f32x4 per thread)
        float4 gbuf[8];
        const float* hb = history + ((size_t)b * KK + n0) * HH;
        #pragma unroll
        for (int j = 0; j < 8; ++j)
            gbuf[j] = *(const float4*)(hb + (size_t)(r0 + 8 * j) * HH + c4);

        __syncthreads();                 // previous tile's compute done
        #pragma unroll
        for (int j = 0; j < 8; ++j) {
            half4 hv;
            hv[0] = (_Float16)gbuf[j].x; hv[1] = (_Float16)gbuf[j].y;
            hv[2] = (_Float16)gbuf[j].z; hv[3] = (_Float16)gbuf[j].w;
            *(half4*)&Ks[(r0 + 8 * j) * KS_STR + c4] = hv;
        }
        __syncthreads();                 // Ks ready
        // stage 2: transpose Ks -> Vt[h][key]
        {
            half8 ra0, ra1, rb0, rb1;
            #pragma unroll
            for (int i = 0; i < 8; ++i) {
                U32H t2; t2.u = *(const unsigned int*)&Ks[(n0t + i) * KS_STR + h0];
                ra0[i] = t2.h[0]; rb0[i] = t2.h[1];
            }
            #pragma unroll
            for (int i = 8; i < 16; ++i) {
                U32H t2; t2.u = *(const unsigned int*)&Ks[(n0t + i) * KS_STR + h0];
                ra1[i - 8] = t2.h[0]; rb1[i - 8] = t2.h[1];
            }
            *(half8*)&Vt[(h0    ) * VT_STR + n0t    ] = ra0;
            *(half8*)&Vt[(h0    ) * VT_STR + n0t + 8] = ra1;
            *(half8*)&Vt[(h0 + 1) * VT_STR + n0t    ] = rb0;
            *(half8*)&Vt[(h0 + 1) * VT_STR + n0t + 8] = rb1;
        }
        __syncthreads();                 // Vt ready

        // ---- S^T = K.Q^T for both strips (each kf read feeds 2 MFMAs) ----
        f32x4 Sa[4], Sb[4];
        #pragma unroll
        for (int nt = 0; nt < 4; ++nt) {
            f32x4 aa = zero4, ab = zero4;
            #pragma unroll
            for (int s4 = 0; s4 < 4; ++s4) {
                half8 kf = *(half8*)&Ks[(nt * 16 + lc) * KS_STR + 32 * s4 + quad * 8];
                aa = __builtin_amdgcn_mfma_f32_16x16x32_f16(kf, qfa[s4], aa, 0, 0, 0);
                ab = __builtin_amdgcn_mfma_f32_16x16x32_f16(kf, qfb[s4], ab, 0, 0, 0);
            }
            Sa[nt] = aa; Sb[nt] = ab;
        }

        // ---- online softmax (log2 domain) ----
        float tmaxA = Sa[0][0], tmaxB = Sb[0][0];
        #pragma unroll
        for (int nt = 0; nt < 4; ++nt)
            #pragma unroll
            for (int r = 0; r < 4; ++r) {
                tmaxA = fmaxf(tmaxA, Sa[nt][r]);
                tmaxB = fmaxf(tmaxB, Sb[nt][r]);
            }
        tmaxA = fmaxf(tmaxA, __shfl_xor(tmaxA, 16, 64));
        tmaxA = fmaxf(tmaxA, __shfl_xor(tmaxA, 32, 64));
        tmaxB = fmaxf(tmaxB, __shfl_xor(tmaxB, 16, 64));
        tmaxB = fmaxf(tmaxB, __shfl_xor(tmaxB, 32, 64));

        const float nmA = fmaxf(rmaxA, tmaxA);
        const float nmB = fmaxf(rmaxB, tmaxB);
        const float alphaA = exp2f(rmaxA - nmA);
        const float alphaB = exp2f(rmaxB - nmB);
        rmaxA = nmA; rmaxB = nmB;

        #pragma unroll
        for (int ct = 0; ct < 8; ++ct) { Oa[ct] *= alphaA; Ob[ct] *= alphaB; }
        OsumA *= alphaA; OsumB *= alphaB;

        // ---- P = exp2(S - nm) -> f16 regs; PV + ones-rowsum via 16x16x16
        //      (B-frag k=quad*4+j matches S^T C-layout row=quad*4+r exactly) ----
        #pragma unroll
        for (int nt = 0; nt < 4; ++nt) {
            half4 pba, pbb;
            #pragma unroll
            for (int r = 0; r < 4; ++r) {
                pba[r] = (_Float16)exp2f(Sa[nt][r] - nmA);
                pbb[r] = (_Float16)exp2f(Sb[nt][r] - nmB);
            }
            OsumA = __builtin_amdgcn_mfma_f32_16x16x16f16(ones4, pba, OsumA, 0, 0, 0);
            OsumB = __builtin_amdgcn_mfma_f32_16x16x16f16(ones4, pbb, OsumB, 0, 0, 0);
            #pragma unroll
            for (int ct = 0; ct < 8; ++ct) {
                half4 va = *(half4*)&Vt[(ct * 16 + lc) * VT_STR + nt * 16 + quad * 4];
                Oa[ct] = __builtin_amdgcn_mfma_f32_16x16x16f16(va, pba, Oa[ct], 0, 0, 0);
                Ob[ct] = __builtin_amdgcn_mfma_f32_16x16x16f16(va, pbb, Ob[ct], 0, 0, 0);
            }
        }
    }

    const int qA = wave * 32 + lc;        // strip A local q-row
    if (splits == 1) {
        const float invA = 1.0f / OsumA[0];
        const float invB = 1.0f / OsumB[0];
        float* orowA = out + ((size_t)b * QQ + m0 + qA) * HH;
        float* orowB = orowA + 16 * HH;
        #pragma unroll
        for (int ct = 0; ct < 8; ++ct) {
            f32x4 va = Oa[ct] * invA;
            f32x4 vb = Ob[ct] * invB;
            *(f32x4*)&orowA[ct * 16 + quad * 4] = va;
            *(f32x4*)&orowB[ct * 16 + quad * 4] = vb;
        }
        return;
    }

    // ---- write partials as f32 (full 64B-sector pattern: 4 quads x 16B) ----
    const size_t mBase = (size_t)splits * OSPLIT;
    const size_t lBase = mBase + (size_t)splits * MLSPLIT;
    float* poA = ws + ((size_t)s * NGROUPS + g) * ((size_t)BM * HH) + (size_t)qA * HH;
    float* poB = poA + 16 * HH;
    #pragma unroll
    for (int ct = 0; ct < 8; ++ct) {
        *(f32x4*)&poA[ct * 16 + quad * 4] = Oa[ct];
        *(f32x4*)&poB[ct * 16 + quad * 4] = Ob[ct];
    }
    if (quad == 0) {
        const size_t idx = (size_t)(s * NGROUPS + g) * BM + qA;
        ws[mBase + idx]      = rmaxA;
        ws[lBase + idx]      = OsumA[0];
        ws[mBase + idx + 16] = rmaxB;
        ws[lBase + idx + 16] = OsumB[0];
    }
}

__global__ void attn_combine(const float* __restrict__ ws,
                             float* __restrict__ out,
                             int splits) {
    // XCD swizzle: batch = blockIdx&7 so partial reads hit the L2 that wrote them.
    const int b      = blockIdx.x & 7;
    const int qchunk = blockIdx.x >> 3;          // 0..255, 8 q-rows each
    const int h4 = (threadIdx.x & 31) * 4;
    const int q  = qchunk * 8 + (threadIdx.x >> 5);
    const int g  = b * 16 + (q >> 7);
    const int qr = q & 127;

    const size_t mBase = (size_t)splits * OSPLIT;
    const size_t lBase = mBase + (size_t)splits * MLSPLIT;

    float ms[SPLITS_MAX];
    float M = -3.0e38f;
    for (int sp = 0; sp < splits; ++sp) {
        ms[sp] = ws[mBase + (size_t)(sp * NGROUPS + g) * BM + qr];
        M = fmaxf(M, ms[sp]);
    }
    float denom = 0.f;
    f32x4 val = {0.f, 0.f, 0.f, 0.f};
    for (int sp = 0; sp < splits; ++sp) {
        const float w = exp2f(ms[sp] - M);
        denom += w * ws[lBase + (size_t)(sp * NGROUPS + g) * BM + qr];
        const f32x4 ov = *(const f32x4*)&ws[(size_t)(sp * NGROUPS + g) * ((size_t)BM * HH)
                                            + (size_t)qr * HH + h4];
        val += w * ov;
    }
    const float inv = 1.0f / denom;
    *(f32x4*)&out[((size_t)b * QQ + q) * HH + h4] = val * inv;
}

extern "C" void kernel_launch(void* const* d_in, const int* in_sizes, int n_in,
                              void* d_out, int out_size, void* d_ws, size_t ws_size,
                              hipStream_t stream) {
    const float* out_state = (const float*)d_in[0];
    const float* history   = (const float*)d_in[1];
    float* out = (float*)d_out;
    float* ws  = (float*)d_ws;

    int splits = 1;
    const int cands[5] = {8, 6, 4, 3, 2};
    for (int i = 0; i < 5; ++i) {
        const size_t bytes = (size_t)cands[i] * (OSPLIT + 2 * MLSPLIT) * 4;
        if (ws_size >= bytes) { splits = cands[i]; break; }
    }

    attn_main<<<dim3(NGROUPS * splits), dim3(256), 0, stream>>>(out_state, history, out, ws, splits);
    if (splits > 1)
        attn_combine<<<dim3(2048), dim3(256), 0, stream>>>(ws, out, splits);
}